// Round 5
// baseline (532.800 us; speedup 1.0000x reference)
//
#include <hip/hip_runtime.h>

#define DD 128
#define NB 8
#define KTOT 1152   // 1024 (agg: k = kk*8 + b) + 128 (self-loop h)
#define TN 32       // nodes per fused-kernel block

typedef unsigned int uint_t;
typedef __attribute__((ext_vector_type(8))) _Float16 half8v;
typedef __attribute__((ext_vector_type(4))) float f32x4;

// ---------------------------------------------------------------------------
// Wc[layer][feat][k]: k<1024 -> bases[b=k&7][kk=k>>3][feat]; else loop_w[k-1024][feat]
// ---------------------------------------------------------------------------
__global__ __launch_bounds__(256) void k_prep_w(
    const float* __restrict__ bases1, const float* __restrict__ loopw1,
    const float* __restrict__ bases2, const float* __restrict__ loopw2,
    _Float16* __restrict__ Wc)
{
  int i = blockIdx.x * 256 + threadIdx.x;          // 2*128*1152
  if (i >= 2 * DD * KTOT) return;
  int layer = i / (DD * KTOT);
  int rem   = i % (DD * KTOT);
  int feat  = rem / KTOT;
  int k     = rem % KTOT;
  const float* basesL = layer ? bases2 : bases1;
  const float* loopwL = layer ? loopw2 : loopw1;
  float v;
  if (k < 1024) {
    int kk = k >> 3, b = k & 7;
    v = basesL[((size_t)b * DD + kk) * DD + feat];
  } else {
    v = loopwL[(size_t)(k - 1024) * DD + feat];
  }
  Wc[i] = (_Float16)v;
}

// cast h (fp32, ids indirection) -> fp16 [N][128]
__global__ __launch_bounds__(256) void k_cast(
    const float* __restrict__ h, const int* __restrict__ ids,
    _Float16* __restrict__ hf, int N)
{
  int i = blockIdx.x * 256 + threadIdx.x;
  if (i >= N * (DD / 8)) return;
  int n  = i / (DD / 8);
  int k8 = (i % (DD / 8)) * 8;
  int row = ids ? ids[n] : n;
  const float* hp = h + (size_t)row * DD + k8;
  float4 v0 = *(const float4*)hp;
  float4 v1 = *(const float4*)(hp + 4);
  union { _Float16 e[8]; uint4 q; } p;
  p.e[0]=(_Float16)v0.x; p.e[1]=(_Float16)v0.y; p.e[2]=(_Float16)v0.z; p.e[3]=(_Float16)v0.w;
  p.e[4]=(_Float16)v1.x; p.e[5]=(_Float16)v1.y; p.e[6]=(_Float16)v1.z; p.e[7]=(_Float16)v1.w;
  *(uint4*)&hf[(size_t)n * DD + k8] = p.q;
}

// ------------------------------- CSR by dst --------------------------------
__global__ __launch_bounds__(256) void k_zero(int* __restrict__ p, int n)
{
  int i = blockIdx.x * 256 + threadIdx.x;
  if (i < n) p[i] = 0;
}

__global__ __launch_bounds__(256) void k_hist(
    const int* __restrict__ dst, int* __restrict__ cnt, int E)
{
  int e = blockIdx.x * 256 + threadIdx.x;
  if (e < E) atomicAdd(&cnt[dst[e]], 1);
}

__global__ __launch_bounds__(256) void k_bsum(
    const int* __restrict__ cnt, int* __restrict__ bsum, int N)
{
  __shared__ int s[256];
  int i = blockIdx.x * 256 + threadIdx.x;
  s[threadIdx.x] = (i < N) ? cnt[i] : 0;
  __syncthreads();
  for (int off = 128; off > 0; off >>= 1) {
    if (threadIdx.x < off) s[threadIdx.x] += s[threadIdx.x + off];
    __syncthreads();
  }
  if (threadIdx.x == 0) bsum[blockIdx.x] = s[0];
}

__global__ __launch_bounds__(256) void k_scanb(
    const int* __restrict__ bsum, int* __restrict__ boff, int nb)
{
  __shared__ int s[256];
  int t = threadIdx.x;
  int own = (t < nb) ? bsum[t] : 0;
  s[t] = own;
  __syncthreads();
  for (int off = 1; off < 256; off <<= 1) {
    int v = (t >= off) ? s[t - off] : 0;
    __syncthreads();
    s[t] += v;
    __syncthreads();
  }
  if (t < nb) boff[t] = s[t] - own;     // exclusive
}

__global__ __launch_bounds__(256) void k_scan3(
    const int* __restrict__ cnt, const int* __restrict__ boff,
    int* __restrict__ row_start, int N)
{
  __shared__ int s[256];
  int t = threadIdx.x;
  int i = blockIdx.x * 256 + t;
  int v = (i < N) ? cnt[i] : 0;
  s[t] = v;
  __syncthreads();
  for (int off = 1; off < 256; off <<= 1) {
    int u = (t >= off) ? s[t - off] : 0;
    __syncthreads();
    s[t] += u;
    __syncthreads();
  }
  if (i < N) row_start[i] = boff[blockIdx.x] + s[t] - v;
}

__global__ __launch_bounds__(256) void k_place(
    const int* __restrict__ dst, const int* __restrict__ row_start,
    int* __restrict__ cursor, int* __restrict__ perm, int E)
{
  int e = blockIdx.x * 256 + threadIdx.x;
  if (e < E) {
    int v = dst[e];
    int slot = row_start[v] + atomicAdd(&cursor[v], 1);
    perm[slot] = e;
  }
}

// ---------------------------------------------------------------------------
// Linearize edge payload into CSR slot order: psrc[i] = src of i-th slot,
// cX[i][b] = wcompX[etype,b]*norm (precomputed coefficients, both layers).
// All reads: perm linear + small resident arrays; all writes linear.
// ---------------------------------------------------------------------------
__global__ __launch_bounds__(256) void k_payload(
    const int* __restrict__ perm, const int* __restrict__ src,
    const int* __restrict__ etype, const float* __restrict__ norm,
    const float* __restrict__ wcomp1, const float* __restrict__ wcomp2,
    int* __restrict__ psrc, float* __restrict__ c1, float* __restrict__ c2,
    int E)
{
  int i = blockIdx.x * 256 + threadIdx.x;
  if (i >= E) return;
  int e = perm[i];
  psrc[i] = src[e];
  int t = etype[e];
  float nm = norm[e];
  const float* w1 = wcomp1 + t * NB;
  const float* w2 = wcomp2 + t * NB;
  float4 a, b;
  a.x=w1[0]*nm; a.y=w1[1]*nm; a.z=w1[2]*nm; a.w=w1[3]*nm;
  b.x=w1[4]*nm; b.y=w1[5]*nm; b.z=w1[6]*nm; b.w=w1[7]*nm;
  *(float4*)&c1[(size_t)i * 8]     = a;
  *(float4*)&c1[(size_t)i * 8 + 4] = b;
  a.x=w2[0]*nm; a.y=w2[1]*nm; a.z=w2[2]*nm; a.w=w2[3]*nm;
  b.x=w2[4]*nm; b.y=w2[5]*nm; b.z=w2[6]*nm; b.w=w2[7]*nm;
  *(float4*)&c2[(size_t)i * 8]     = a;
  *(float4*)&c2[(size_t)i * 8 + 4] = b;
}

// ---------------------------------------------------------------------------
// Fused aggregate + K=1152 MFMA GEMM per 32-node tile.
// Phase 1: per-node aggregation into swizzled LDS B-tile [32][1152] fp16
//          (cols 0..1023 = agg k=kk*8+b; cols 1024..1151 = own h row).
// Phase 2: out[n][feat] = sum_k B[n][k]*Wc[feat][k] + bias  via MFMA.
// Swizzle: byte_in_row ^= (row&7)<<4  (bijective, kills stride-2304 conflicts)
// LAYER==1: relu -> fp16 outh.  LAYER==2: fp32 outf.
// ---------------------------------------------------------------------------
union F8 { float4 v[2]; float f[8]; };

template <int LAYER>
__global__ __launch_bounds__(256, 2) void k_fused(
    const int* __restrict__ rowst, const int* __restrict__ cnt,
    const int* __restrict__ psrc, const float* __restrict__ c8,
    const _Float16* __restrict__ hf,     // [N][128] layer input
    const _Float16* __restrict__ Wc,     // [128][1152] feat-major
    const float* __restrict__ bias,
    float* __restrict__ outf, _Float16* __restrict__ outh, int N)
{
  __shared__ __align__(16) char sB[TN * 2304];   // 72 KB
  const int n0   = blockIdx.x * TN;
  const int wv   = threadIdx.x >> 6;
  const int lane = threadIdx.x & 63;
  const int l15  = lane & 15, l4 = lane >> 4;
  const uint_t* hf32 = (const uint_t*)hf;

  // ---------------- phase 1: aggregate into LDS ----------------
  for (int r = wv; r < TN; r += 4) {
    int v = n0 + r;
    char* rowp = sB + r * 2304;
    if (v >= N) {           // tail: zero the row so MFMA reads clean zeros
      uint4 z = make_uint4(0, 0, 0, 0);
      for (int c = lane; c < 144; c += 64) *(uint4*)(rowp + c * 16) = z;
      continue;
    }
    const int beg = rowst[v];
    const int num = cnt[v];
    const int swzr = (r & 7) << 4;

    float ax[NB] = {}, ay[NB] = {};
    int i = 0;
    for (; i + 2 <= num; i += 2) {
      int s0 = psrc[beg + i], s1 = psrc[beg + i + 1];
      uint_t u0 = hf32[(size_t)s0 * 64 + lane];
      uint_t u1 = hf32[(size_t)s1 * 64 + lane];
      F8 cc0, cc1;
      cc0.v[0] = *(const float4*)&c8[(size_t)(beg + i) * 8];
      cc0.v[1] = *(const float4*)&c8[(size_t)(beg + i) * 8 + 4];
      cc1.v[0] = *(const float4*)&c8[(size_t)(beg + i + 1) * 8];
      cc1.v[1] = *(const float4*)&c8[(size_t)(beg + i + 1) * 8 + 4];
      union { uint_t u; _Float16 h[2]; } w0, w1;
      w0.u = u0; w1.u = u1;
      float lo0 = (float)w0.h[0], hi0 = (float)w0.h[1];
      float lo1 = (float)w1.h[0], hi1 = (float)w1.h[1];
      #pragma unroll
      for (int b = 0; b < NB; b++) {
        ax[b] += cc0.f[b] * lo0; ay[b] += cc0.f[b] * hi0;
        ax[b] += cc1.f[b] * lo1; ay[b] += cc1.f[b] * hi1;
      }
    }
    if (i < num) {
      int s0 = psrc[beg + i];
      uint_t u0 = hf32[(size_t)s0 * 64 + lane];
      F8 cc0;
      cc0.v[0] = *(const float4*)&c8[(size_t)(beg + i) * 8];
      cc0.v[1] = *(const float4*)&c8[(size_t)(beg + i) * 8 + 4];
      union { uint_t u; _Float16 h[2]; } w0;
      w0.u = u0;
      float lo0 = (float)w0.h[0], hi0 = (float)w0.h[1];
      #pragma unroll
      for (int b = 0; b < NB; b++) { ax[b] += cc0.f[b] * lo0; ay[b] += cc0.f[b] * hi0; }
    }

    // write agg part: lane owns cols lane*16..+15 (two 16B chunks)
    union { _Float16 e[8]; uint4 q; } p0, p1;
    #pragma unroll
    for (int b = 0; b < NB; b++) { p0.e[b] = (_Float16)ax[b]; p1.e[b] = (_Float16)ay[b]; }
    *(uint4*)(rowp + ((lane * 32)      ^ swzr)) = p0.q;
    *(uint4*)(rowp + ((lane * 32 + 16) ^ swzr)) = p1.q;
    // copy own h row into cols 1024..1151 (4B per lane)
    uint_t hv = hf32[(size_t)v * 64 + lane];
    *(uint_t*)(rowp + ((2048 + lane * 4) ^ swzr)) = hv;
  }
  __syncthreads();

  // ---------------- phase 2: MFMA from LDS ----------------
  f32x4 acc[2][2];
  #pragma unroll
  for (int a = 0; a < 2; a++)
    #pragma unroll
    for (int b = 0; b < 2; b++) acc[a][b] = (f32x4)0.f;

  #pragma unroll
  for (int ks = 0; ks < KTOT / 32; ks++) {
    const int k0 = ks * 32;
    half8v af[2], bf[2];
    #pragma unroll
    for (int mf = 0; mf < 2; mf++)
      af[mf] = *(const half8v*)&Wc[(size_t)(wv * 32 + mf * 16 + l15) * KTOT + k0 + l4 * 8];
    #pragma unroll
    for (int nf = 0; nf < 2; nf++) {
      int row = nf * 16 + l15;
      bf[nf] = *(const half8v*)(sB + row * 2304 + (((k0 + l4 * 8) * 2) ^ ((row & 7) << 4)));
    }
    #pragma unroll
    for (int mf = 0; mf < 2; mf++)
      #pragma unroll
      for (int nf = 0; nf < 2; nf++)
        acc[mf][nf] = __builtin_amdgcn_mfma_f32_16x16x32_f16(af[mf], bf[nf], acc[mf][nf], 0, 0, 0);
  }

  // C layout: col(=node) = lane&15, row(=feat) = (lane>>4)*4 + r
  #pragma unroll
  for (int mf = 0; mf < 2; mf++)
    #pragma unroll
    for (int nf = 0; nf < 2; nf++) {
      int n = n0 + nf * 16 + l15;
      if (n >= N) continue;
      int feat = wv * 32 + mf * 16 + l4 * 4;
      if (LAYER == 1) {
        union { _Float16 e[4]; uint2 q; } p;
        #pragma unroll
        for (int r = 0; r < 4; r++)
          p.e[r] = (_Float16)fmaxf(acc[mf][nf][r] + bias[feat + r], 0.f);
        *(uint2*)&outh[(size_t)n * DD + feat] = p.q;
      } else {
        float4 o;
        o.x = acc[mf][nf][0] + bias[feat + 0];
        o.y = acc[mf][nf][1] + bias[feat + 1];
        o.z = acc[mf][nf][2] + bias[feat + 2];
        o.w = acc[mf][nf][3] + bias[feat + 3];
        *(float4*)&outf[(size_t)n * DD + feat] = o;
      }
    }
}

extern "C" void kernel_launch(void* const* d_in, const int* in_sizes, int n_in,
                              void* d_out, int out_size, void* d_ws, size_t ws_size,
                              hipStream_t stream)
{
  const int*   h_ids     = (const int*)d_in[0];
  const int*   src       = (const int*)d_in[1];
  const int*   dst       = (const int*)d_in[2];
  const int*   etype     = (const int*)d_in[3];
  const float* norm      = (const float*)d_in[4];
  const float* embedding = (const float*)d_in[5];
  const float* w_comp1   = (const float*)d_in[6];
  const float* bases1    = (const float*)d_in[7];
  const float* loop_w1   = (const float*)d_in[8];
  const float* bias1     = (const float*)d_in[9];
  const float* w_comp2   = (const float*)d_in[10];
  const float* bases2    = (const float*)d_in[11];
  const float* loop_w2   = (const float*)d_in[12];
  const float* bias2     = (const float*)d_in[13];

  const int N = in_sizes[0];
  const int E = in_sizes[1];
  const int NBLK = (N + 255) / 256;     // <= 256 (N <= 65536)

  // ---- workspace carve-up (256B aligned) ----
  char* base = (char*)d_ws;
  size_t off = 0;
  auto alloc = [&](size_t bytes) -> char* {
    char* p = base + off;
    off += (bytes + 255) & ~(size_t)255;
    return p;
  };
  _Float16* hfp  = (_Float16*)alloc((size_t)N * DD * 2);     // 12.8 MB
  _Float16* h1h  = (_Float16*)alloc((size_t)N * DD * 2);     // 12.8 MB
  _Float16* Wc   = (_Float16*)alloc((size_t)2 * DD * KTOT * 2);
  int*      cnt    = (int*)   alloc((size_t)2 * N * 4);      // cnt + cursor
  int*      cursor = cnt + N;
  int*      rowst  = (int*)   alloc((size_t)N * 4);
  int*      bsum   = (int*)   alloc(256 * 4);
  int*      boff   = (int*)   alloc(256 * 4);
  int*      perm   = (int*)   alloc((size_t)E * 4);
  int*      psrc   = (int*)   alloc((size_t)E * 4);
  float*    c1     = (float*) alloc((size_t)E * 8 * 4);      // 19.2 MB
  float*    c2     = (float*) alloc((size_t)E * 8 * 4);      // 19.2 MB
  float*    out    = (float*)d_out;

  // ---- build CSR by dst (reused by both layers) ----
  k_zero <<<(2 * N + 255) / 256, 256, 0, stream>>>(cnt, 2 * N);
  k_hist <<<(E + 255) / 256, 256, 0, stream>>>(dst, cnt, E);
  k_bsum <<<NBLK, 256, 0, stream>>>(cnt, bsum, N);
  k_scanb<<<1, 256, 0, stream>>>(bsum, boff, NBLK);
  k_scan3<<<NBLK, 256, 0, stream>>>(cnt, boff, rowst, N);
  k_place<<<(E + 255) / 256, 256, 0, stream>>>(dst, rowst, cursor, perm, E);
  k_payload<<<(E + 255) / 256, 256, 0, stream>>>(perm, src, etype, norm,
                                                 w_comp1, w_comp2, psrc, c1, c2, E);

  // ---- weights -> fp16 combined/transposed ----
  k_prep_w<<<(2 * DD * KTOT + 255) / 256, 256, 0, stream>>>(bases1, loop_w1, bases2, loop_w2, Wc);

  dim3 gf((N + TN - 1) / TN);

  // ---- layer 1 ----
  k_cast<<<(N * (DD / 8) + 255) / 256, 256, 0, stream>>>(embedding, h_ids, hfp, N);
  k_fused<1><<<gf, 256, 0, stream>>>(rowst, cnt, psrc, c1, hfp, Wc, bias1,
                                     nullptr, h1h, N);
  // ---- layer 2 ----
  k_fused<2><<<gf, 256, 0, stream>>>(rowst, cnt, psrc, c2, h1h,
                                     Wc + (size_t)DD * KTOT, bias2, out, nullptr, N);
}

// Round 6
// 401.345 us; speedup vs baseline: 1.3275x; 1.3275x over previous
//
#include <hip/hip_runtime.h>

#define DD 128
#define NB 8
#define KTOT 1152   // 1024 (agg: k = kk*8 + b) + 128 (self-loop h)

typedef unsigned int uint_t;
typedef __attribute__((ext_vector_type(8))) _Float16 half8v;
typedef __attribute__((ext_vector_type(4))) float f32x4;

// ---------------------------------------------------------------------------
// WcA[layer][ks][feat][j] = W[feat][k=ks*32+j]   (A-fragment-coalesced layout)
//   k<1024 -> bases[b=k&7][kk=k>>3][feat]; else loop_w[k-1024][feat]
// ---------------------------------------------------------------------------
__global__ __launch_bounds__(256) void k_prep_w(
    const float* __restrict__ bases1, const float* __restrict__ loopw1,
    const float* __restrict__ bases2, const float* __restrict__ loopw2,
    _Float16* __restrict__ WcA)
{
  int i = blockIdx.x * 256 + threadIdx.x;          // 2*36*128*32
  if (i >= 2 * 36 * DD * 32) return;
  int layer = i / (36 * DD * 32);
  int rem   = i % (36 * DD * 32);
  int ks    = rem / (DD * 32);
  int rem2  = rem % (DD * 32);
  int feat  = rem2 / 32;
  int j     = rem2 % 32;
  int k     = ks * 32 + j;
  const float* basesL = layer ? bases2 : bases1;
  const float* loopwL = layer ? loopw2 : loopw1;
  float v;
  if (k < 1024) {
    int kk = k >> 3, b = k & 7;
    v = basesL[((size_t)b * DD + kk) * DD + feat];
  } else {
    v = loopwL[(size_t)(k - 1024) * DD + feat];
  }
  WcA[i] = (_Float16)v;
}

// cast h (fp32, ids indirection) -> fp16 [N][128]
__global__ __launch_bounds__(256) void k_cast(
    const float* __restrict__ h, const int* __restrict__ ids,
    _Float16* __restrict__ hf, int N)
{
  int i = blockIdx.x * 256 + threadIdx.x;
  if (i >= N * (DD / 8)) return;
  int n  = i / (DD / 8);
  int k8 = (i % (DD / 8)) * 8;
  int row = ids ? ids[n] : n;
  const float* hp = h + (size_t)row * DD + k8;
  float4 v0 = *(const float4*)hp;
  float4 v1 = *(const float4*)(hp + 4);
  union { _Float16 e[8]; uint4 q; } p;
  p.e[0]=(_Float16)v0.x; p.e[1]=(_Float16)v0.y; p.e[2]=(_Float16)v0.z; p.e[3]=(_Float16)v0.w;
  p.e[4]=(_Float16)v1.x; p.e[5]=(_Float16)v1.y; p.e[6]=(_Float16)v1.z; p.e[7]=(_Float16)v1.w;
  *(uint4*)&hf[(size_t)n * DD + k8] = p.q;
}

// ------------------------------- CSR by dst --------------------------------
__global__ __launch_bounds__(256) void k_zero(int* __restrict__ p, int n)
{
  int i = blockIdx.x * 256 + threadIdx.x;
  if (i < n) p[i] = 0;
}

__global__ __launch_bounds__(256) void k_hist(
    const int* __restrict__ dst, int* __restrict__ cnt, int E)
{
  int e = blockIdx.x * 256 + threadIdx.x;
  if (e < E) atomicAdd(&cnt[dst[e]], 1);
}

__global__ __launch_bounds__(256) void k_bsum(
    const int* __restrict__ cnt, int* __restrict__ bsum, int N)
{
  __shared__ int s[256];
  int i = blockIdx.x * 256 + threadIdx.x;
  s[threadIdx.x] = (i < N) ? cnt[i] : 0;
  __syncthreads();
  for (int off = 128; off > 0; off >>= 1) {
    if (threadIdx.x < off) s[threadIdx.x] += s[threadIdx.x + off];
    __syncthreads();
  }
  if (threadIdx.x == 0) bsum[blockIdx.x] = s[0];
}

__global__ __launch_bounds__(256) void k_scanb(
    const int* __restrict__ bsum, int* __restrict__ boff, int nb)
{
  __shared__ int s[256];
  int t = threadIdx.x;
  int own = (t < nb) ? bsum[t] : 0;
  s[t] = own;
  __syncthreads();
  for (int off = 1; off < 256; off <<= 1) {
    int v = (t >= off) ? s[t - off] : 0;
    __syncthreads();
    s[t] += v;
    __syncthreads();
  }
  if (t < nb) boff[t] = s[t] - own;     // exclusive
}

__global__ __launch_bounds__(256) void k_scan3(
    const int* __restrict__ cnt, const int* __restrict__ boff,
    int* __restrict__ row_start, int N)
{
  __shared__ int s[256];
  int t = threadIdx.x;
  int i = blockIdx.x * 256 + t;
  int v = (i < N) ? cnt[i] : 0;
  s[t] = v;
  __syncthreads();
  for (int off = 1; off < 256; off <<= 1) {
    int u = (t >= off) ? s[t - off] : 0;
    __syncthreads();
    s[t] += u;
    __syncthreads();
  }
  if (i < N) row_start[i] = boff[blockIdx.x] + s[t] - v;
}

__global__ __launch_bounds__(256) void k_place(
    const int* __restrict__ dst, const int* __restrict__ row_start,
    int* __restrict__ cursor, int* __restrict__ perm, int E)
{
  int e = blockIdx.x * 256 + threadIdx.x;
  if (e < E) {
    int v = dst[e];
    int slot = row_start[v] + atomicAdd(&cursor[v], 1);
    perm[slot] = e;
  }
}

// ---------------------------------------------------------------------------
// Linearize edge payload into CSR slot order: psrc[i] = src of i-th slot,
// cX[i][b] = wcompX[etype,b]*norm (precomputed coefficients, both layers).
// ---------------------------------------------------------------------------
__global__ __launch_bounds__(256) void k_payload(
    const int* __restrict__ perm, const int* __restrict__ src,
    const int* __restrict__ etype, const float* __restrict__ norm,
    const float* __restrict__ wcomp1, const float* __restrict__ wcomp2,
    int* __restrict__ psrc, float* __restrict__ c1, float* __restrict__ c2,
    int E)
{
  int i = blockIdx.x * 256 + threadIdx.x;
  if (i >= E) return;
  int e = perm[i];
  psrc[i] = src[e];
  int t = etype[e];
  float nm = norm[e];
  const float* w1 = wcomp1 + t * NB;
  const float* w2 = wcomp2 + t * NB;
  float4 a, b;
  a.x=w1[0]*nm; a.y=w1[1]*nm; a.z=w1[2]*nm; a.w=w1[3]*nm;
  b.x=w1[4]*nm; b.y=w1[5]*nm; b.z=w1[6]*nm; b.w=w1[7]*nm;
  *(float4*)&c1[(size_t)i * 8]     = a;
  *(float4*)&c1[(size_t)i * 8 + 4] = b;
  a.x=w2[0]*nm; a.y=w2[1]*nm; a.z=w2[2]*nm; a.w=w2[3]*nm;
  b.x=w2[4]*nm; b.y=w2[5]*nm; b.z=w2[6]*nm; b.w=w2[7]*nm;
  *(float4*)&c2[(size_t)i * 8]     = a;
  *(float4*)&c2[(size_t)i * 8 + 4] = b;
}

// ---------------------------------------------------------------------------
// Aggregation: one wave per dst node, linear payload, chain-depth-1 gather.
// agg[v][kk*8+b] = sum_edges c8[slot][b] * hf[psrc[slot]][kk]   (fp16)
// lane owns feats 2*lane, 2*lane+1 -> contiguous 32B store at agg[v]+lane*32B.
// ---------------------------------------------------------------------------
union F8 { float4 v[2]; float f[8]; };

__global__ __launch_bounds__(256) void k_agg(
    const int* __restrict__ rowst, const int* __restrict__ cnt,
    const int* __restrict__ psrc, const float* __restrict__ c8,
    const _Float16* __restrict__ hf,
    _Float16* __restrict__ agg, int N)
{
  int v = blockIdx.x * 4 + (threadIdx.x >> 6);
  if (v >= N) return;
  int lane = threadIdx.x & 63;
  const uint_t* hf32 = (const uint_t*)hf;
  const int beg = rowst[v];
  const int num = cnt[v];

  float ax[NB] = {}, ay[NB] = {};
  int i = 0;
  for (; i + 2 <= num; i += 2) {
    int s0 = psrc[beg + i], s1 = psrc[beg + i + 1];
    uint_t u0 = hf32[(size_t)s0 * 64 + lane];
    uint_t u1 = hf32[(size_t)s1 * 64 + lane];
    F8 cc0, cc1;
    cc0.v[0] = *(const float4*)&c8[(size_t)(beg + i) * 8];
    cc0.v[1] = *(const float4*)&c8[(size_t)(beg + i) * 8 + 4];
    cc1.v[0] = *(const float4*)&c8[(size_t)(beg + i + 1) * 8];
    cc1.v[1] = *(const float4*)&c8[(size_t)(beg + i + 1) * 8 + 4];
    union { uint_t u; _Float16 h[2]; } w0, w1;
    w0.u = u0; w1.u = u1;
    float lo0 = (float)w0.h[0], hi0 = (float)w0.h[1];
    float lo1 = (float)w1.h[0], hi1 = (float)w1.h[1];
    #pragma unroll
    for (int b = 0; b < NB; b++) {
      ax[b] += cc0.f[b] * lo0; ay[b] += cc0.f[b] * hi0;
      ax[b] += cc1.f[b] * lo1; ay[b] += cc1.f[b] * hi1;
    }
  }
  if (i < num) {
    int s0 = psrc[beg + i];
    uint_t u0 = hf32[(size_t)s0 * 64 + lane];
    F8 cc0;
    cc0.v[0] = *(const float4*)&c8[(size_t)(beg + i) * 8];
    cc0.v[1] = *(const float4*)&c8[(size_t)(beg + i) * 8 + 4];
    union { uint_t u; _Float16 h[2]; } w0;
    w0.u = u0;
    float lo0 = (float)w0.h[0], hi0 = (float)w0.h[1];
    #pragma unroll
    for (int b = 0; b < NB; b++) { ax[b] += cc0.f[b] * lo0; ay[b] += cc0.f[b] * hi0; }
  }

  union { _Float16 e[8]; uint4 q; } p0, p1;
  #pragma unroll
  for (int b = 0; b < NB; b++) { p0.e[b] = (_Float16)ax[b]; p1.e[b] = (_Float16)ay[b]; }
  uint4* dstp = (uint4*)&agg[(size_t)v * 1024 + lane * 16];
  dstp[0] = p0.q;
  dstp[1] = p1.q;
}

// ---------------------------------------------------------------------------
// MFMA GEMM, K=1152: out[v][feat] = sum_k B[v][k]*W[feat][k] + bias
// B = [agg[v] (k<1024) | hf[v] (k>=1024)].  64-node tile, 4 waves over feats.
// A loads from WcA are contiguous 1KB per wave-instr; B loads are 16 full
// 64B lines per instr.  No LDS, partial unroll to avoid spills.
// LAYER==1: relu -> fp16 outh.  LAYER==2: fp32 outf.
// ---------------------------------------------------------------------------
template <int LAYER>
__global__ __launch_bounds__(256) void k_mm(
    const _Float16* __restrict__ agg,   // [N][1024]
    const _Float16* __restrict__ hf,    // [N][128]
    const _Float16* __restrict__ WcA,   // [36][128][32]
    const float* __restrict__ bias,
    float* __restrict__ outf, _Float16* __restrict__ outh, int N)
{
  const int n0   = blockIdx.x * 64;
  const int wv   = threadIdx.x >> 6;
  const int lane = threadIdx.x & 63;
  const int l15  = lane & 15, l4 = lane >> 4;

  f32x4 acc[2][4];
  #pragma unroll
  for (int a = 0; a < 2; a++)
    #pragma unroll
    for (int b = 0; b < 4; b++) acc[a][b] = (f32x4)0.f;

  int nodes[4];
  #pragma unroll
  for (int nf = 0; nf < 4; nf++) {
    int n = n0 + nf * 16 + l15;
    nodes[nf] = (n < N) ? n : (N - 1);
  }

  const int fbase = wv * 32 + l15;      // + mf*16
  const int koff  = l4 * 8;

  #pragma unroll 2
  for (int ks = 0; ks < 32; ks++) {
    half8v af[2], bfr[4];
    #pragma unroll
    for (int mf = 0; mf < 2; mf++)
      af[mf] = *(const half8v*)&WcA[((size_t)ks * DD + fbase + mf * 16) * 32 + koff];
    #pragma unroll
    for (int nf = 0; nf < 4; nf++)
      bfr[nf] = *(const half8v*)&agg[(size_t)nodes[nf] * 1024 + ks * 32 + koff];
    #pragma unroll
    for (int mf = 0; mf < 2; mf++)
      #pragma unroll
      for (int nf = 0; nf < 4; nf++)
        acc[mf][nf] = __builtin_amdgcn_mfma_f32_16x16x32_f16(af[mf], bfr[nf], acc[mf][nf], 0, 0, 0);
  }
  #pragma unroll 2
  for (int ks = 32; ks < 36; ks++) {
    half8v af[2], bfr[4];
    #pragma unroll
    for (int mf = 0; mf < 2; mf++)
      af[mf] = *(const half8v*)&WcA[((size_t)ks * DD + fbase + mf * 16) * 32 + koff];
    #pragma unroll
    for (int nf = 0; nf < 4; nf++)
      bfr[nf] = *(const half8v*)&hf[(size_t)nodes[nf] * DD + (ks - 32) * 32 + koff];
    #pragma unroll
    for (int mf = 0; mf < 2; mf++)
      #pragma unroll
      for (int nf = 0; nf < 4; nf++)
        acc[mf][nf] = __builtin_amdgcn_mfma_f32_16x16x32_f16(af[mf], bfr[nf], acc[mf][nf], 0, 0, 0);
  }

  // C layout: col(=node) = lane&15, row(=feat) = (lane>>4)*4 + r
  #pragma unroll
  for (int mf = 0; mf < 2; mf++)
    #pragma unroll
    for (int nf = 0; nf < 4; nf++) {
      int n = n0 + nf * 16 + l15;
      if (n >= N) continue;
      int feat = wv * 32 + mf * 16 + l4 * 4;
      if (LAYER == 1) {
        union { _Float16 e[4]; uint2 q; } p;
        #pragma unroll
        for (int r = 0; r < 4; r++)
          p.e[r] = (_Float16)fmaxf(acc[mf][nf][r] + bias[feat + r], 0.f);
        *(uint2*)&outh[(size_t)n * DD + feat] = p.q;
      } else {
        float4 o;
        o.x = acc[mf][nf][0] + bias[feat + 0];
        o.y = acc[mf][nf][1] + bias[feat + 1];
        o.z = acc[mf][nf][2] + bias[feat + 2];
        o.w = acc[mf][nf][3] + bias[feat + 3];
        *(float4*)&outf[(size_t)n * DD + feat] = o;
      }
    }
}

extern "C" void kernel_launch(void* const* d_in, const int* in_sizes, int n_in,
                              void* d_out, int out_size, void* d_ws, size_t ws_size,
                              hipStream_t stream)
{
  const int*   h_ids     = (const int*)d_in[0];
  const int*   src       = (const int*)d_in[1];
  const int*   dst       = (const int*)d_in[2];
  const int*   etype     = (const int*)d_in[3];
  const float* norm      = (const float*)d_in[4];
  const float* embedding = (const float*)d_in[5];
  const float* w_comp1   = (const float*)d_in[6];
  const float* bases1    = (const float*)d_in[7];
  const float* loop_w1   = (const float*)d_in[8];
  const float* bias1     = (const float*)d_in[9];
  const float* w_comp2   = (const float*)d_in[10];
  const float* bases2    = (const float*)d_in[11];
  const float* loop_w2   = (const float*)d_in[12];
  const float* bias2     = (const float*)d_in[13];

  const int N = in_sizes[0];
  const int E = in_sizes[1];
  const int NBLK = (N + 255) / 256;     // <= 256 (N <= 65536)

  // ---- workspace carve-up (256B aligned) ----
  char* base = (char*)d_ws;
  size_t off = 0;
  auto alloc = [&](size_t bytes) -> char* {
    char* p = base + off;
    off += (bytes + 255) & ~(size_t)255;
    return p;
  };
  _Float16* agg  = (_Float16*)alloc((size_t)N * 1024 * 2);   // 102.4 MB
  _Float16* hfp  = (_Float16*)alloc((size_t)N * DD * 2);     // 12.8 MB
  _Float16* h1h  = (_Float16*)alloc((size_t)N * DD * 2);     // 12.8 MB
  _Float16* WcA  = (_Float16*)alloc((size_t)2 * 36 * DD * 32 * 2);
  int*      cnt    = (int*)   alloc((size_t)2 * N * 4);      // cnt + cursor
  int*      cursor = cnt + N;
  int*      rowst  = (int*)   alloc((size_t)N * 4);
  int*      bsum   = (int*)   alloc(256 * 4);
  int*      boff   = (int*)   alloc(256 * 4);
  int*      perm   = (int*)   alloc((size_t)E * 4);
  int*      psrc   = (int*)   alloc((size_t)E * 4);
  float*    c1     = (float*) alloc((size_t)E * 8 * 4);      // 19.2 MB
  float*    c2     = (float*) alloc((size_t)E * 8 * 4);      // 19.2 MB
  float*    out    = (float*)d_out;

  // ---- build CSR by dst (reused by both layers) ----
  k_zero <<<(2 * N + 255) / 256, 256, 0, stream>>>(cnt, 2 * N);
  k_hist <<<(E + 255) / 256, 256, 0, stream>>>(dst, cnt, E);
  k_bsum <<<NBLK, 256, 0, stream>>>(cnt, bsum, N);
  k_scanb<<<1, 256, 0, stream>>>(bsum, boff, NBLK);
  k_scan3<<<NBLK, 256, 0, stream>>>(cnt, boff, rowst, N);
  k_place<<<(E + 255) / 256, 256, 0, stream>>>(dst, rowst, cursor, perm, E);
  k_payload<<<(E + 255) / 256, 256, 0, stream>>>(perm, src, etype, norm,
                                                 w_comp1, w_comp2, psrc, c1, c2, E);

  // ---- weights -> fp16 A-coalesced layout ----
  k_prep_w<<<(2 * 36 * DD * 32 + 255) / 256, 256, 0, stream>>>(bases1, loop_w1, bases2, loop_w2, WcA);

  dim3 gmm((N + 63) / 64);
  int gagg = (N + 3) / 4;

  // ---- layer 1 ----
  k_cast<<<(N * (DD / 8) + 255) / 256, 256, 0, stream>>>(embedding, h_ids, hfp, N);
  k_agg<<<gagg, 256, 0, stream>>>(rowst, cnt, psrc, c1, hfp, agg, N);
  k_mm<1><<<gmm, 256, 0, stream>>>(agg, hfp, WcA, bias1, nullptr, h1h, N);

  // ---- layer 2 ----
  k_agg<<<gagg, 256, 0, stream>>>(rowst, cnt, psrc, c2, h1h, agg, N);
  k_mm<2><<<gmm, 256, 0, stream>>>(agg, h1h, WcA + (size_t)36 * DD * 32, bias2, out, nullptr, N);
}

// Round 7
// 287.624 us; speedup vs baseline: 1.8524x; 1.3954x over previous
//
#include <hip/hip_runtime.h>

#define DD 128
#define NB 8
#define KTOT 1152   // 1024 (agg: k = kk*8 + b) + 128 (self-loop h)

typedef unsigned int uint_t;
typedef __attribute__((ext_vector_type(8))) _Float16 half8v;
typedef __attribute__((ext_vector_type(4))) float f32x4;

static __device__ __forceinline__ void gld_lds16(const _Float16* g, _Float16* l)
{
  __builtin_amdgcn_global_load_lds(
      (const __attribute__((address_space(1))) void*)g,
      (__attribute__((address_space(3))) void*)l, 16, 0, 0);
}

// ---------------------------------------------------------------------------
// WcA[layer][ks][feat][j] = W[feat][k=ks*32+j]   (A-fragment-coalesced layout)
//   k<1024 -> bases[b=k&7][kk=k>>3][feat]; else loop_w[k-1024][feat]
// ---------------------------------------------------------------------------
__global__ __launch_bounds__(256) void k_prep_w(
    const float* __restrict__ bases1, const float* __restrict__ loopw1,
    const float* __restrict__ bases2, const float* __restrict__ loopw2,
    _Float16* __restrict__ WcA)
{
  int i = blockIdx.x * 256 + threadIdx.x;          // 2*36*128*32
  if (i >= 2 * 36 * DD * 32) return;
  int layer = i / (36 * DD * 32);
  int rem   = i % (36 * DD * 32);
  int ks    = rem / (DD * 32);
  int rem2  = rem % (DD * 32);
  int feat  = rem2 / 32;
  int j     = rem2 % 32;
  int k     = ks * 32 + j;
  const float* basesL = layer ? bases2 : bases1;
  const float* loopwL = layer ? loopw2 : loopw1;
  float v;
  if (k < 1024) {
    int kk = k >> 3, b = k & 7;
    v = basesL[((size_t)b * DD + kk) * DD + feat];
  } else {
    v = loopwL[(size_t)(k - 1024) * DD + feat];
  }
  WcA[i] = (_Float16)v;
}

// cast h (fp32, ids indirection) -> fp16 [N][128]
__global__ __launch_bounds__(256) void k_cast(
    const float* __restrict__ h, const int* __restrict__ ids,
    _Float16* __restrict__ hf, int N)
{
  int i = blockIdx.x * 256 + threadIdx.x;
  if (i >= N * (DD / 8)) return;
  int n  = i / (DD / 8);
  int k8 = (i % (DD / 8)) * 8;
  int row = ids ? ids[n] : n;
  const float* hp = h + (size_t)row * DD + k8;
  float4 v0 = *(const float4*)hp;
  float4 v1 = *(const float4*)(hp + 4);
  union { _Float16 e[8]; uint4 q; } p;
  p.e[0]=(_Float16)v0.x; p.e[1]=(_Float16)v0.y; p.e[2]=(_Float16)v0.z; p.e[3]=(_Float16)v0.w;
  p.e[4]=(_Float16)v1.x; p.e[5]=(_Float16)v1.y; p.e[6]=(_Float16)v1.z; p.e[7]=(_Float16)v1.w;
  *(uint4*)&hf[(size_t)n * DD + k8] = p.q;
}

// ------------------------------- CSR by dst --------------------------------
__global__ __launch_bounds__(256) void k_zero(int* __restrict__ p, int n)
{
  int i = blockIdx.x * 256 + threadIdx.x;
  if (i < n) p[i] = 0;
}

__global__ __launch_bounds__(256) void k_hist(
    const int* __restrict__ dst, int* __restrict__ cnt, int E)
{
  int e = blockIdx.x * 256 + threadIdx.x;
  if (e < E) atomicAdd(&cnt[dst[e]], 1);
}

__global__ __launch_bounds__(256) void k_bsum(
    const int* __restrict__ cnt, int* __restrict__ bsum, int N)
{
  __shared__ int s[256];
  int i = blockIdx.x * 256 + threadIdx.x;
  s[threadIdx.x] = (i < N) ? cnt[i] : 0;
  __syncthreads();
  for (int off = 128; off > 0; off >>= 1) {
    if (threadIdx.x < off) s[threadIdx.x] += s[threadIdx.x + off];
    __syncthreads();
  }
  if (threadIdx.x == 0) bsum[blockIdx.x] = s[0];
}

__global__ __launch_bounds__(256) void k_scanb(
    const int* __restrict__ bsum, int* __restrict__ boff, int nb)
{
  __shared__ int s[256];
  int t = threadIdx.x;
  int own = (t < nb) ? bsum[t] : 0;
  s[t] = own;
  __syncthreads();
  for (int off = 1; off < 256; off <<= 1) {
    int v = (t >= off) ? s[t - off] : 0;
    __syncthreads();
    s[t] += v;
    __syncthreads();
  }
  if (t < nb) boff[t] = s[t] - own;     // exclusive
}

__global__ __launch_bounds__(256) void k_scan3(
    const int* __restrict__ cnt, const int* __restrict__ boff,
    int* __restrict__ row_start, int N)
{
  __shared__ int s[256];
  int t = threadIdx.x;
  int i = blockIdx.x * 256 + t;
  int v = (i < N) ? cnt[i] : 0;
  s[t] = v;
  __syncthreads();
  for (int off = 1; off < 256; off <<= 1) {
    int u = (t >= off) ? s[t - off] : 0;
    __syncthreads();
    s[t] += u;
    __syncthreads();
  }
  if (i < N) row_start[i] = boff[blockIdx.x] + s[t] - v;
}

__global__ __launch_bounds__(256) void k_place(
    const int* __restrict__ dst, const int* __restrict__ row_start,
    int* __restrict__ cursor, int* __restrict__ perm, int E)
{
  int e = blockIdx.x * 256 + threadIdx.x;
  if (e < E) {
    int v = dst[e];
    int slot = row_start[v] + atomicAdd(&cursor[v], 1);
    perm[slot] = e;
  }
}

// ---------------------------------------------------------------------------
// Linearize edge payload into CSR slot order: psrc[i] = src of i-th slot,
// cX[i][b] = fp16( wcompX[etype,b]*norm )  (16B per edge per layer).
// ---------------------------------------------------------------------------
__global__ __launch_bounds__(256) void k_payload(
    const int* __restrict__ perm, const int* __restrict__ src,
    const int* __restrict__ etype, const float* __restrict__ norm,
    const float* __restrict__ wcomp1, const float* __restrict__ wcomp2,
    int* __restrict__ psrc, _Float16* __restrict__ c1, _Float16* __restrict__ c2,
    int E)
{
  int i = blockIdx.x * 256 + threadIdx.x;
  if (i >= E) return;
  int e = perm[i];
  psrc[i] = src[e];
  int t = etype[e];
  float nm = norm[e];
  const float* w1 = wcomp1 + t * NB;
  const float* w2 = wcomp2 + t * NB;
  union { _Float16 h[8]; uint4 q; } p;
  #pragma unroll
  for (int b = 0; b < NB; b++) p.h[b] = (_Float16)(w1[b] * nm);
  *(uint4*)&c1[(size_t)i * 8] = p.q;
  #pragma unroll
  for (int b = 0; b < NB; b++) p.h[b] = (_Float16)(w2[b] * nm);
  *(uint4*)&c2[(size_t)i * 8] = p.q;
}

// ---------------------------------------------------------------------------
// Aggregation: one wave per dst node, linear payload, chain-depth-1 gather,
// unroll 4 (4 independent 256B gathers in flight per wave).
// agg[v][kk*8+b] = sum_edges c8[slot][b] * hf[psrc[slot]][kk]   (fp16)
// ---------------------------------------------------------------------------
__global__ __launch_bounds__(256) void k_agg(
    const int* __restrict__ rowst, const int* __restrict__ cnt,
    const int* __restrict__ psrc, const _Float16* __restrict__ c8,
    const _Float16* __restrict__ hf,
    _Float16* __restrict__ agg, int N)
{
  int v = blockIdx.x * 4 + (threadIdx.x >> 6);
  if (v >= N) return;
  int lane = threadIdx.x & 63;
  const uint_t* hf32 = (const uint_t*)hf;
  const int beg = rowst[v];
  const int num = cnt[v];

  float ax[NB] = {}, ay[NB] = {};
  int i = 0;
  for (; i + 4 <= num; i += 4) {
    int s0 = psrc[beg + i],     s1 = psrc[beg + i + 1];
    int s2 = psrc[beg + i + 2], s3 = psrc[beg + i + 3];
    uint_t u0 = hf32[(size_t)s0 * 64 + lane];
    uint_t u1 = hf32[(size_t)s1 * 64 + lane];
    uint_t u2 = hf32[(size_t)s2 * 64 + lane];
    uint_t u3 = hf32[(size_t)s3 * 64 + lane];
    half8v q0 = *(const half8v*)&c8[(size_t)(beg + i) * 8];
    half8v q1 = *(const half8v*)&c8[(size_t)(beg + i + 1) * 8];
    half8v q2 = *(const half8v*)&c8[(size_t)(beg + i + 2) * 8];
    half8v q3 = *(const half8v*)&c8[(size_t)(beg + i + 3) * 8];
    union { uint_t u; _Float16 h[2]; } w;
    w.u = u0; float lo0 = (float)w.h[0], hi0 = (float)w.h[1];
    w.u = u1; float lo1 = (float)w.h[0], hi1 = (float)w.h[1];
    w.u = u2; float lo2 = (float)w.h[0], hi2 = (float)w.h[1];
    w.u = u3; float lo3 = (float)w.h[0], hi3 = (float)w.h[1];
    #pragma unroll
    for (int b = 0; b < NB; b++) {
      float c0 = (float)q0[b], c1_ = (float)q1[b];
      float c2_ = (float)q2[b], c3 = (float)q3[b];
      ax[b] += c0 * lo0 + c1_ * lo1 + c2_ * lo2 + c3 * lo3;
      ay[b] += c0 * hi0 + c1_ * hi1 + c2_ * hi2 + c3 * hi3;
    }
  }
  for (; i < num; i++) {
    int s0 = psrc[beg + i];
    uint_t u0 = hf32[(size_t)s0 * 64 + lane];
    half8v q0 = *(const half8v*)&c8[(size_t)(beg + i) * 8];
    union { uint_t u; _Float16 h[2]; } w;
    w.u = u0; float lo0 = (float)w.h[0], hi0 = (float)w.h[1];
    #pragma unroll
    for (int b = 0; b < NB; b++) {
      float c0 = (float)q0[b];
      ax[b] += c0 * lo0; ay[b] += c0 * hi0;
    }
  }

  union { _Float16 e[8]; uint4 q; } p0, p1;
  #pragma unroll
  for (int b = 0; b < NB; b++) { p0.e[b] = (_Float16)ax[b]; p1.e[b] = (_Float16)ay[b]; }
  uint4* dstp = (uint4*)&agg[(size_t)v * 1024 + lane * 16];
  dstp[0] = p0.q;
  dstp[1] = p1.q;
}

// ---------------------------------------------------------------------------
// MFMA GEMM, K=1152, BK=64, LDS-shared B with global_load_lds double-buffer.
// Block: 64 nodes x 128 feats, 4 waves (wave = 32 feats).
// LDS buffer layout: [kslot 0..7][node 0..63][16B]  (8KB; kslot = 8 k-elems)
//   -> ds_read_b128 at (l4+sub*4)*1024 + row*16: optimal bank spread.
// Stage: wave wv issues 2 global_load_lds (kslot wv, wv+4), lane = node.
// LAYER==1: relu -> fp16 outh.  LAYER==2: fp32 outf.
// ---------------------------------------------------------------------------
template <int LAYER>
__global__ __launch_bounds__(256) void k_mm(
    const _Float16* __restrict__ agg,   // [N][1024]
    const _Float16* __restrict__ hf,    // [N][128]
    const _Float16* __restrict__ WcA,   // [36][128][32]
    const float* __restrict__ bias,
    float* __restrict__ outf, _Float16* __restrict__ outh, int N)
{
  __shared__ _Float16 sB[2][4096];      // 2 x 8KB

  const int n0   = blockIdx.x * 64;
  const int wv   = threadIdx.x >> 6;
  const int lane = threadIdx.x & 63;
  const int l15  = lane & 15, l4 = lane >> 4;

  int nodeL = n0 + lane; if (nodeL >= N) nodeL = N - 1;   // stage-source clamp

  f32x4 acc[2][4];
  #pragma unroll
  for (int a = 0; a < 2; a++)
    #pragma unroll
    for (int b = 0; b < 4; b++) acc[a][b] = (f32x4)0.f;

  const int fbase = wv * 32 + l15;      // + mf*16
  const int koff  = l4 * 8;

  // stage K-pair t into buf: kslots wv (ks=2t) and wv+4 (ks=2t+1)
  auto STAGE = [&](int buf, int t) {
    const _Float16 *g0, *g1;
    if (t < 16) {
      g0 = &agg[(size_t)nodeL * 1024 + (2 * t)     * 32 + wv * 8];
      g1 = &agg[(size_t)nodeL * 1024 + (2 * t + 1) * 32 + wv * 8];
    } else {
      g0 = &hf[(size_t)nodeL * DD + (2 * t - 32) * 32 + wv * 8];
      g1 = &hf[(size_t)nodeL * DD + (2 * t - 31) * 32 + wv * 8];
    }
    gld_lds16(g0, &sB[buf][ wv      * 512]);
    gld_lds16(g1, &sB[buf][(wv + 4) * 512]);
  };

  auto COMPUTE = [&](int buf, int t) {
    #pragma unroll
    for (int sub = 0; sub < 2; sub++) {
      const int ks = 2 * t + sub;
      half8v af[2], bfr[4];
      #pragma unroll
      for (int mf = 0; mf < 2; mf++)
        af[mf] = *(const half8v*)&WcA[((size_t)ks * DD + fbase + mf * 16) * 32 + koff];
      #pragma unroll
      for (int nf = 0; nf < 4; nf++)
        bfr[nf] = *(const half8v*)&sB[buf][(l4 + sub * 4) * 512 + (nf * 16 + l15) * 8];
      #pragma unroll
      for (int mf = 0; mf < 2; mf++)
        #pragma unroll
        for (int nf = 0; nf < 4; nf++)
          acc[mf][nf] = __builtin_amdgcn_mfma_f32_16x16x32_f16(af[mf], bfr[nf], acc[mf][nf], 0, 0, 0);
    }
  };

  STAGE(0, 0);
  __syncthreads();                       // drains vmcnt(0) before barrier
  int cur = 0;
  for (int t = 0; t < 17; t++) {
    STAGE(cur ^ 1, t + 1);
    COMPUTE(cur, t);
    __syncthreads();                     // stage done + all reads done
    cur ^= 1;
  }
  COMPUTE(cur, 17);

  // C layout: col(=node) = lane&15, row(=feat) = (lane>>4)*4 + r
  #pragma unroll
  for (int mf = 0; mf < 2; mf++)
    #pragma unroll
    for (int nf = 0; nf < 4; nf++) {
      int n = n0 + nf * 16 + l15;
      if (n >= N) continue;
      int feat = wv * 32 + mf * 16 + l4 * 4;
      if (LAYER == 1) {
        union { _Float16 e[4]; uint2 q; } p;
        #pragma unroll
        for (int r = 0; r < 4; r++)
          p.e[r] = (_Float16)fmaxf(acc[mf][nf][r] + bias[feat + r], 0.f);
        *(uint2*)&outh[(size_t)n * DD + feat] = p.q;
      } else {
        float4 o;
        o.x = acc[mf][nf][0] + bias[feat + 0];
        o.y = acc[mf][nf][1] + bias[feat + 1];
        o.z = acc[mf][nf][2] + bias[feat + 2];
        o.w = acc[mf][nf][3] + bias[feat + 3];
        *(float4*)&outf[(size_t)n * DD + feat] = o;
      }
    }
}

extern "C" void kernel_launch(void* const* d_in, const int* in_sizes, int n_in,
                              void* d_out, int out_size, void* d_ws, size_t ws_size,
                              hipStream_t stream)
{
  const int*   h_ids     = (const int*)d_in[0];
  const int*   src       = (const int*)d_in[1];
  const int*   dst       = (const int*)d_in[2];
  const int*   etype     = (const int*)d_in[3];
  const float* norm      = (const float*)d_in[4];
  const float* embedding = (const float*)d_in[5];
  const float* w_comp1   = (const float*)d_in[6];
  const float* bases1    = (const float*)d_in[7];
  const float* loop_w1   = (const float*)d_in[8];
  const float* bias1     = (const float*)d_in[9];
  const float* w_comp2   = (const float*)d_in[10];
  const float* bases2    = (const float*)d_in[11];
  const float* loop_w2   = (const float*)d_in[12];
  const float* bias2     = (const float*)d_in[13];

  const int N = in_sizes[0];
  const int E = in_sizes[1];
  const int NBLK = (N + 255) / 256;     // <= 256 (N <= 65536)

  // ---- workspace carve-up (256B aligned) ----
  char* base = (char*)d_ws;
  size_t off = 0;
  auto alloc = [&](size_t bytes) -> char* {
    char* p = base + off;
    off += (bytes + 255) & ~(size_t)255;
    return p;
  };
  _Float16* agg  = (_Float16*)alloc((size_t)N * 1024 * 2);   // 102.4 MB
  _Float16* hfp  = (_Float16*)alloc((size_t)N * DD * 2);     // 12.8 MB
  _Float16* h1h  = (_Float16*)alloc((size_t)N * DD * 2);     // 12.8 MB
  _Float16* WcA  = (_Float16*)alloc((size_t)2 * 36 * DD * 32 * 2);
  int*      cnt    = (int*)   alloc((size_t)2 * N * 4);      // cnt + cursor
  int*      cursor = cnt + N;
  int*      rowst  = (int*)   alloc((size_t)N * 4);
  int*      bsum   = (int*)   alloc(256 * 4);
  int*      boff   = (int*)   alloc(256 * 4);
  int*      perm   = (int*)   alloc((size_t)E * 4);
  int*      psrc   = (int*)   alloc((size_t)E * 4);
  _Float16* c1     = (_Float16*)alloc((size_t)E * 8 * 2);    // 9.6 MB
  _Float16* c2     = (_Float16*)alloc((size_t)E * 8 * 2);    // 9.6 MB
  float*    out    = (float*)d_out;

  // ---- build CSR by dst (reused by both layers) ----
  k_zero <<<(2 * N + 255) / 256, 256, 0, stream>>>(cnt, 2 * N);
  k_hist <<<(E + 255) / 256, 256, 0, stream>>>(dst, cnt, E);
  k_bsum <<<NBLK, 256, 0, stream>>>(cnt, bsum, N);
  k_scanb<<<1, 256, 0, stream>>>(bsum, boff, NBLK);
  k_scan3<<<NBLK, 256, 0, stream>>>(cnt, boff, rowst, N);
  k_place<<<(E + 255) / 256, 256, 0, stream>>>(dst, rowst, cursor, perm, E);
  k_payload<<<(E + 255) / 256, 256, 0, stream>>>(perm, src, etype, norm,
                                                 w_comp1, w_comp2, psrc, c1, c2, E);

  // ---- weights -> fp16 A-coalesced layout ----
  k_prep_w<<<(2 * 36 * DD * 32 + 255) / 256, 256, 0, stream>>>(bases1, loop_w1, bases2, loop_w2, WcA);

  dim3 gmm((N + 63) / 64);
  int gagg = (N + 3) / 4;

  // ---- layer 1 ----
  k_cast<<<(N * (DD / 8) + 255) / 256, 256, 0, stream>>>(embedding, h_ids, hfp, N);
  k_agg<<<gagg, 256, 0, stream>>>(rowst, cnt, psrc, c1, hfp, agg, N);
  k_mm<1><<<gmm, 256, 0, stream>>>(agg, hfp, WcA, bias1, nullptr, h1h, N);

  // ---- layer 2 ----
  k_agg<<<gagg, 256, 0, stream>>>(rowst, cnt, psrc, c2, h1h, agg, N);
  k_mm<2><<<gmm, 256, 0, stream>>>(agg, h1h, WcA + (size_t)36 * DD * 32, bias2, out, nullptr, N);
}